// Round 11
// baseline (214.123 us; speedup 1.0000x reference)
//
#include <hip/hip_runtime.h>

#define NB 64      // batch
#define SEQ 305    // sequence length
#define DIM 2048   // hidden
#define NP 256     // patches
#define NT 48      // task tokens
#define NKEEP 128  // kept patches
#define SOUT 177   // 1 + 128 + 48
#define KS 16      // d-depth per LDS stage (dbuf: 2 x 13 KB)

static_assert(1 + NP + NT == SEQ, "layout");

constexpr float kScale = 0.022097086912079608f;  // 1/sqrt(2048)

// ---------------------------------------------------------------------------
// K1a: grid (1 + 2*ndc, 64), 128 thr. x==0: fused static copy of cls+task.
// Else: xi=x-1, dci=xi>>1, pt=xi&1. Tile 128p x 48t x dchunk, micro-tile 8x6
// (validated). LDS DOUBLE-BUFFERED [2][d][row] (stride 140 p / 64 t-slot),
// ONE barrier per chunk: compute(cur) ; lwrite(next-buf) ; gload(next+1);
// sync. lwrite overlaps other waves' compute; KS=16 makes staging writes
// span 32 banks (2-way = free, vs 4-way at KS=32).
// Hazards: lwrite(buf X) only after all waves passed the sync that sealed
// the last compute reading X (prev iteration's barrier).
// ssq fused into staging, 4-lane shfl-reduced (fixed order, deterministic).
// ---------------------------------------------------------------------------
__global__ __launch_bounds__(128) void k1a_partial_gemm(
    const float* __restrict__ tokens, float* __restrict__ rpart,
    float* __restrict__ ssqP, float* __restrict__ ssqT,
    float* __restrict__ out0, int ndc, int dchunk) {
  const int b = blockIdx.y;
  const int t = threadIdx.x;

  if (blockIdx.x == 0) {
    // copy cls (row 0 -> 0) and task rows (257..304 -> 129..176)
#pragma unroll 2
    for (int l = 0; l < 196; ++l) {
      int u = l * 128 + t;  // 49 rows * 512 f4
      int row = u >> 9, c = u & 511;
      int srow = (row == 0) ? 0 : (256 + row);
      int drow = (row == 0) ? 0 : (128 + row);
      *(float4*)(out0 + ((size_t)b * SOUT + drow) * DIM + (size_t)c * 4) =
          *(const float4*)(tokens + ((size_t)b * SEQ + srow) * DIM + (size_t)c * 4);
    }
    return;
  }

  const int xi = blockIdx.x - 1;
  const int dci = xi >> 1;
  const int pt = xi & 1;
  const int pg = t >> 3;  // 0..15: p-rows pg*8..pg*8+7 (of this 128-half)
  const int tg = t & 7;   // 0..7:  t-cols tg*6..tg*6+5

  __shared__ __align__(16) float pC[2][KS][140];  // [buf][d][p-row]
  __shared__ __align__(16) float tC[2][KS][64];   // [buf][d][t-slot]

  const float* pbase =
      tokens + ((size_t)b * SEQ + 1 + pt * 128) * DIM + (size_t)dci * dchunk;
  const float* tbase =
      tokens + ((size_t)b * SEQ + 1 + NP) * DIM + (size_t)dci * dchunk;

  float4 st[6];
  float acc[8][6] = {};
  float ssqa[6] = {};
  const int nchunk = dchunk / KS;

  // staging map: u = t + 128*l. u<512: p (row=u>>2 in 0..127, c4=u&3);
  // 512<=u<704: t (v=u-512: row=v>>2 in 0..47, c4=v&3). l=0..3 pure-p,
  // l=4 pure-t, l=5 t for t<64 (branches resolve per l at compile time).
  auto gload = [&](int ck) {
#pragma unroll
    for (int l = 0; l < 6; ++l) {
      int u = t + 128 * l;
      if (u < 512) {
        int row = u >> 2, c4 = u & 3;
        st[l] = *(const float4*)(pbase + (size_t)row * DIM + ck * KS + c4 * 4);
      } else if (u < 704) {
        int v = u - 512;
        int row = v >> 2, c4 = v & 3;
        st[l] = *(const float4*)(tbase + (size_t)row * DIM + ck * KS + c4 * 4);
      }
    }
  };
  auto lwrite = [&](int bf) {
#pragma unroll
    for (int l = 0; l < 6; ++l) {
      int u = t + 128 * l;
      float4 v = st[l];
      if (u < 512) {
        int row = u >> 2, c4 = u & 3;
        pC[bf][c4 * 4 + 0][row] = v.x;
        pC[bf][c4 * 4 + 1][row] = v.y;
        pC[bf][c4 * 4 + 2][row] = v.z;
        pC[bf][c4 * 4 + 3][row] = v.w;
        ssqa[l] += v.x * v.x + v.y * v.y + v.z * v.z + v.w * v.w;
      } else if (u < 704) {
        int vv = u - 512;
        int row = vv >> 2, c4 = vv & 3;
        int slot = (row / 6) * 8 + (row % 6);
        tC[bf][c4 * 4 + 0][slot] = v.x;
        tC[bf][c4 * 4 + 1][slot] = v.y;
        tC[bf][c4 * 4 + 2][slot] = v.z;
        tC[bf][c4 * 4 + 3][slot] = v.w;
        ssqa[l] += v.x * v.x + v.y * v.y + v.z * v.z + v.w * v.w;
      }
    }
  };

  gload(0);
  lwrite(0);
  if (nchunk > 1) gload(1);
  __syncthreads();

  for (int ck = 0; ck < nchunk; ++ck) {
    const int bf = ck & 1;
#pragma unroll 4
    for (int dd = 0; dd < KS; ++dd) {
      float4 p0 = *(const float4*)&pC[bf][dd][pg * 8];
      float4 p1 = *(const float4*)&pC[bf][dd][pg * 8 + 4];
      float4 t0 = *(const float4*)&tC[bf][dd][tg * 8];
      float2 t1 = *(const float2*)&tC[bf][dd][tg * 8 + 4];
      float pa[8] = {p0.x, p0.y, p0.z, p0.w, p1.x, p1.y, p1.z, p1.w};
      float tb[6] = {t0.x, t0.y, t0.z, t0.w, t1.x, t1.y};
#pragma unroll
      for (int i = 0; i < 8; ++i)
#pragma unroll
        for (int j = 0; j < 6; ++j) acc[i][j] += pa[i] * tb[j];
    }
    if (ck + 1 < nchunk) lwrite((ck + 1) & 1);  // overlaps other waves' compute
    if (ck + 2 < nchunk) gload(ck + 2);         // latency hidden by next compute
    __syncthreads();  // one barrier per chunk
  }

  // partial R, transposed: rpart[(b*ndc+dci)][jg][256], cols pt*128+pg*8
  float* rp = rpart + ((size_t)b * ndc + dci) * (NT * NP) + pt * 128;
#pragma unroll
  for (int j = 0; j < 6; ++j) {
    int jg = tg * 6 + j;
    float4 v0 = {acc[0][j], acc[1][j], acc[2][j], acc[3][j]};
    float4 v1 = {acc[4][j], acc[5][j], acc[6][j], acc[7][j]};
    *(float4*)(rp + jg * NP + pg * 8) = v0;
    *(float4*)(rp + jg * NP + pg * 8 + 4) = v1;
  }

  // ssq: reduce across the 4 staging lanes of each row (fixed order)
#pragma unroll
  for (int l = 0; l < 6; ++l) {
    float s = ssqa[l];
    s += __shfl_down(s, 2, 4);
    s += __shfl_down(s, 1, 4);
    ssqa[l] = s;
  }
  if ((t & 3) == 0) {
#pragma unroll
    for (int l = 0; l < 6; ++l) {
      int u = t + 128 * l;
      if (u < 512) {
        ssqP[((size_t)b * ndc + dci) * NP + pt * 128 + (u >> 2)] = ssqa[l];
      } else if (u < 704) {
        if (pt == 0)
          ssqT[((size_t)b * ndc + dci) * NT + ((u - 512) >> 2)] = ssqa[l];
      }
    }
  }
}

// ---------------------------------------------------------------------------
// K1b: grid (4 pt, 64 b), 256 thr. Sum ndc partials in fixed order
// (deterministic), rms + softmax, write attnp = softmax*invT and
// rn = raw*invP. Inits umax.
// ---------------------------------------------------------------------------
__global__ __launch_bounds__(256) void k1b_reduce_softmax(
    const float* __restrict__ rpart, const float* __restrict__ ssqP,
    const float* __restrict__ ssqT, float* __restrict__ attnp,
    float* __restrict__ rn, unsigned long long* __restrict__ umax, int ndc) {
  const int pt = blockIdx.x;
  const int b = blockIdx.y;
  const int t = threadIdx.x;
  const int r = t & 63;
  const int q = t >> 6;

  __shared__ float L[64][49];
  __shared__ float invPs[64];
  __shared__ float invTs[48];

  float a[12] = {};
  const float* rb = rpart + (size_t)b * ndc * (NT * NP) + pt * 64 + r;
  for (int dci = 0; dci < ndc; ++dci) {
    const float* rp = rb + (size_t)dci * (NT * NP);
#pragma unroll
    for (int j = 0; j < 12; ++j) a[j] += rp[(q * 12 + j) * NP];
  }
#pragma unroll
  for (int j = 0; j < 12; ++j) L[r][q * 12 + j] = a[j];

  if (t < 64) {
    float s = 0.f;
    for (int dci = 0; dci < ndc; ++dci)
      s += ssqP[((size_t)b * ndc + dci) * NP + pt * 64 + t];
    invPs[t] = 1.0f / sqrtf(s * (1.0f / 2048.0f) + 1e-6f);
    umax[(size_t)b * NP + pt * 64 + t] = 0ull;
  } else if (t < 112) {
    int j = t - 64;
    float s = 0.f;
    for (int dci = 0; dci < ndc; ++dci)
      s += ssqT[((size_t)b * ndc + dci) * NT + j];
    invTs[j] = 1.0f / sqrtf(s * (1.0f / 2048.0f) + 1e-6f);
  }
  __syncthreads();

  if (t < 64) {
    const float invp = invPs[t];
    float lg[48];
    float m = -3.4e38f;
#pragma unroll
    for (int j = 0; j < 48; ++j) {
      lg[j] = L[t][j] * invp * invTs[j] * kScale;
      m = fmaxf(m, lg[j]);
    }
    float s = 0.f;
#pragma unroll
    for (int j = 0; j < 48; ++j) {
      lg[j] = expf(lg[j] - m);
      s += lg[j];
    }
    const float is = 1.0f / s;
    float* ao = attnp + ((size_t)b * NP + pt * 64 + t) * NT;
    float* ro = rn + ((size_t)b * NP + pt * 64 + t) * NT;
#pragma unroll
    for (int j = 0; j < 48; ++j) ao[j] = lg[j] * is * invTs[j];
#pragma unroll
    for (int j = 0; j < 48; ++j) ro[j] = L[t][j] * invp;
  }
}

// ---------------------------------------------------------------------------
// K2: score[p][q] = sum_t attn'[p][t] * Rn[q][t], argmax over q folded in via
// packed (mono-float | ~q) atomicMax (order-independent -> deterministic).
// ---------------------------------------------------------------------------
__global__ __launch_bounds__(256) void k2_score_argmax(
    const float* __restrict__ attnp, const float* __restrict__ rn,
    unsigned long long* __restrict__ umax) {
  const int b = blockIdx.y;
  const int qt = blockIdx.x & 3;
  const int pb = blockIdx.x >> 2;
  const int t = threadIdx.x;
  const int tp = t >> 4, tq = t & 15;

  __shared__ float aS[48][68];
  __shared__ float rS[48][68];

  const float* ab = attnp + ((size_t)b * NP + pb * 64) * NT;
  const float* rb = rn + ((size_t)b * NP + qt * 64) * NT;
#pragma unroll
  for (int l = 0; l < 3; ++l) {
    int u = t + 256 * l;  // 64 rows x 12 f4
    int row = u / 12, c4 = u % 12;
    float4 v = *(const float4*)(ab + (size_t)row * NT + c4 * 4);
    aS[c4 * 4 + 0][row] = v.x;
    aS[c4 * 4 + 1][row] = v.y;
    aS[c4 * 4 + 2][row] = v.z;
    aS[c4 * 4 + 3][row] = v.w;
    float4 wv = *(const float4*)(rb + (size_t)row * NT + c4 * 4);
    rS[c4 * 4 + 0][row] = wv.x;
    rS[c4 * 4 + 1][row] = wv.y;
    rS[c4 * 4 + 2][row] = wv.z;
    rS[c4 * 4 + 3][row] = wv.w;
  }
  __syncthreads();

  float acc[4][4] = {};
#pragma unroll
  for (int k = 0; k < 48; ++k) {
    float4 av = *(const float4*)&aS[k][tp * 4];
    float4 rv = *(const float4*)&rS[k][tq * 4];
    float aa[4] = {av.x, av.y, av.z, av.w};
    float rr[4] = {rv.x, rv.y, rv.z, rv.w};
#pragma unroll
    for (int i = 0; i < 4; ++i)
#pragma unroll
      for (int j = 0; j < 4; ++j) acc[i][j] += aa[i] * rr[j];
  }

#pragma unroll
  for (int i = 0; i < 4; ++i) {
    float bs = acc[i][0];
    int bq = qt * 64 + tq * 4;
#pragma unroll
    for (int j = 1; j < 4; ++j) {
      float s = acc[i][j];
      int qq = qt * 64 + tq * 4 + j;
      if (s > bs) {  // strict > keeps smallest q on ties
        bs = s;
        bq = qq;
      }
    }
    unsigned us = __float_as_uint(bs);
    us = (us & 0x80000000u) ? ~us : (us | 0x80000000u);
    unsigned long long key =
        ((unsigned long long)us << 32) | (unsigned long long)(0xFFFFFFFFu - (unsigned)bq);
    for (int o = 8; o >= 1; o >>= 1) {
      unsigned long long ok = __shfl_xor(key, o, 16);
      if (ok > key) key = ok;
    }
    if (tq == 0) atomicMax(&umax[(size_t)b * NP + pb * 64 + tp * 4 + i], key);
  }
}

// ---------------------------------------------------------------------------
// K3: per batch: decode argmax, vote counts, exact rank (count desc, idx asc),
// keep rank<128, emit ascending; gather pos/mask in the same block.
// ---------------------------------------------------------------------------
__global__ __launch_bounds__(256) void k3_select_meta(
    const unsigned long long* __restrict__ umax, const int* __restrict__ pos,
    const int* __restrict__ msk, int* __restrict__ order,
    float* __restrict__ out1, float* __restrict__ out2) {
  const int b = blockIdx.x, t = threadIdx.x;
  __shared__ int cnt[256];
  __shared__ int kept[256];
  __shared__ int sorder[NKEEP];
  cnt[t] = 0;
  __syncthreads();
  unsigned long long key = umax[(size_t)b * NP + t];
  int q = (int)(0xFFFFFFFFu - (unsigned)(key & 0xFFFFFFFFull));
  atomicAdd(&cnt[q], 1);
  __syncthreads();
  const int c = cnt[t];
  int rank = 0;
  for (int u = 0; u < 256; ++u) {
    int cu = cnt[u];
    rank += (cu > c || (cu == c && u < t)) ? 1 : 0;
  }
  kept[t] = (rank < NKEEP) ? 1 : 0;
  __syncthreads();
  if (kept[t]) {
    int posn = 0;
    for (int u = 0; u < t; ++u) posn += kept[u];
    order[b * NKEEP + posn] = t;
    sorder[posn] = t;
  }
  __syncthreads();
  if (t < SOUT) {
    int src;
    if (t == 0) src = 0;
    else if (t < 1 + NKEEP) src = 1 + sorder[t - 1];
    else src = t + (NP - NKEEP);
    out1[b * SOUT + t] = (float)pos[b * SEQ + src];
    out2[b * SOUT + t] = (float)msk[b * SEQ + src];
  }
}

// ---------------------------------------------------------------------------
// K4: gather only the 128 kept patch rows (cls/task copied in k1a).
// ---------------------------------------------------------------------------
__global__ __launch_bounds__(256) void k4_gather_kept(
    const float* __restrict__ tokens, const int* __restrict__ order,
    float* __restrict__ out) {
  const int ki = blockIdx.x;  // 0..127
  const int b = blockIdx.y;
  const int t = threadIdx.x;
  const int src = 1 + order[b * NKEEP + ki];
  const float4* in4 = (const float4*)(tokens + ((size_t)b * SEQ + src) * DIM);
  float4* o4 = (float4*)(out + ((size_t)b * SOUT + 1 + ki) * DIM);
  o4[t] = in4[t];
  o4[t + 256] = in4[t + 256];
}

// ---------------------------------------------------------------------------
extern "C" void kernel_launch(void* const* d_in, const int* in_sizes, int n_in,
                              void* d_out, int out_size, void* d_ws,
                              size_t ws_size, hipStream_t stream) {
  const float* tokens = (const float*)d_in[0];
  const int* pos = (const int*)d_in[1];
  const int* msk = (const int*)d_in[2];

  float* out0 = (float*)d_out;
  float* out1 = out0 + (size_t)NB * SOUT * DIM;
  float* out2 = out1 + (size_t)NB * SOUT;

  // adaptive split-K depth by workspace size
  const size_t fixed = (size_t)(2 * NB * NP * NT) * 4 + (size_t)NB * NP * 8 +
                       (size_t)NB * NKEEP * 4;
  const size_t perndc = (size_t)NB * (NT * NP + NP + NT) * 4;
  int ndc = 16;
  while (ndc > 4 && fixed + (size_t)ndc * perndc > ws_size) ndc >>= 1;
  const int dchunk = DIM / ndc;

  char* ws = (char*)d_ws;
  float* attnp = (float*)ws;                 // NB*NP*NT
  float* rn = attnp + (size_t)NB * NP * NT;  // NB*NP*NT
  unsigned long long* umax = (unsigned long long*)(rn + (size_t)NB * NP * NT);
  int* order = (int*)(umax + (size_t)NB * NP);
  float* rpart = (float*)(order + (size_t)NB * NKEEP);  // NB*ndc*48*256
  float* ssqP = rpart + (size_t)NB * ndc * NT * NP;     // NB*ndc*256
  float* ssqT = ssqP + (size_t)NB * ndc * NP;           // NB*ndc*48

  k1a_partial_gemm<<<dim3(1 + 2 * ndc, NB), 128, 0, stream>>>(
      tokens, rpart, ssqP, ssqT, out0, ndc, dchunk);
  k1b_reduce_softmax<<<dim3(4, NB), 256, 0, stream>>>(rpart, ssqP, ssqT, attnp,
                                                      rn, umax, ndc);
  k2_score_argmax<<<dim3(16, NB), 256, 0, stream>>>(attnp, rn, umax);
  k3_select_meta<<<NB, 256, 0, stream>>>(umax, pos, msk, order, out1, out2);
  k4_gather_kept<<<dim3(NKEEP, NB), 256, 0, stream>>>(tokens, order, out0);
}